// Round 1
// baseline (297.123 us; speedup 1.0000x reference)
//
#include <hip/hip_runtime.h>

// ReadInAttention — 8-stage f32 pipeline.
// v2 gcore: K split across the 4 waves (each wave streams a DISJOINT
// K-quarter of B -> 4x less global/L2 B traffic vs all-waves-same-B),
// 16 rows x float4 cols per thread, dual 8-deep float4 B prefetch,
// A broadcast from LDS via explicit float4 (ds_read_b128) loads,
// cross-wave partial-sum reduction through LDS (48KB, overlaps A tile).

#define DD 768
#define CDIM 384
#define NH 8
#define HD 64
#define INNER 512
#define VV 256

__device__ __forceinline__ void fma4(float4& a, float s, const float4& b) {
  a.x += s * b.x; a.y += s * b.y; a.z += s * b.z; a.w += s * b.w;
}

// One 8-k FMA block over 16 rows (4 groups of 4). A fragments loaded as
// float4 pairs (broadcast ds_read_b128, conflict-free).
__device__ __forceinline__ void fma_chunk(const float* __restrict__ Aw, int lda,
                                          int kk, const float4* b,
                                          float4* acc) {
#pragma unroll
  for (int rg = 0; rg < 4; rg++) {
    const float* ap = Aw + (rg * 4) * lda + kk;
    float4 a0l = *(const float4*)(ap);
    float4 a0h = *(const float4*)(ap + 4);
    float4 a1l = *(const float4*)(ap + lda);
    float4 a1h = *(const float4*)(ap + lda + 4);
    float4 a2l = *(const float4*)(ap + 2 * lda);
    float4 a2h = *(const float4*)(ap + 2 * lda + 4);
    float4 a3l = *(const float4*)(ap + 3 * lda);
    float4 a3h = *(const float4*)(ap + 3 * lda + 4);
    float4* ac = acc + rg * 4;
    fma4(ac[0], a0l.x, b[0]); fma4(ac[1], a1l.x, b[0]);
    fma4(ac[2], a2l.x, b[0]); fma4(ac[3], a3l.x, b[0]);
    fma4(ac[0], a0l.y, b[1]); fma4(ac[1], a1l.y, b[1]);
    fma4(ac[2], a2l.y, b[1]); fma4(ac[3], a3l.y, b[1]);
    fma4(ac[0], a0l.z, b[2]); fma4(ac[1], a1l.z, b[2]);
    fma4(ac[2], a2l.z, b[2]); fma4(ac[3], a3l.z, b[2]);
    fma4(ac[0], a0l.w, b[3]); fma4(ac[1], a1l.w, b[3]);
    fma4(ac[2], a2l.w, b[3]); fma4(ac[3], a3l.w, b[3]);
    fma4(ac[0], a0h.x, b[4]); fma4(ac[1], a1h.x, b[4]);
    fma4(ac[2], a2h.x, b[4]); fma4(ac[3], a3h.x, b[4]);
    fma4(ac[0], a0h.y, b[5]); fma4(ac[1], a1h.y, b[5]);
    fma4(ac[2], a2h.y, b[5]); fma4(ac[3], a3h.y, b[5]);
    fma4(ac[0], a0h.z, b[6]); fma4(ac[1], a1h.z, b[6]);
    fma4(ac[2], a2h.z, b[6]); fma4(ac[3], a3h.z, b[6]);
    fma4(ac[0], a0h.w, b[7]); fma4(ac[1], a1h.w, b[7]);
    fma4(ac[2], a2h.w, b[7]); fma4(ac[3], a3h.w, b[7]);
  }
}

// Per-wave GEMM over a K-quarter: 16 rows x (64 lanes * float4) cols.
// KQ = K/4, multiple of 8, >= 16. Aw already offset to this wave's k0.
// Bp already offset to (wave k0 row, lane col). Dual 8-deep prefetch.
template <int KQ, int NS>
__device__ __forceinline__ void gcore16(const float* __restrict__ Aw, int lda,
                                        const float* __restrict__ Bp,
                                        float4* acc) {
  float4 b0[8], b1[8];
  const float* Bq = Bp;
#pragma unroll
  for (int i = 0; i < 8; i++) b0[i] = *(const float4*)(Bq + (size_t)i * NS);
  Bq += (size_t)8 * NS;
#pragma unroll 1
  for (int kk = 0; kk + 16 <= KQ; kk += 16) {
#pragma unroll
    for (int i = 0; i < 8; i++) b1[i] = *(const float4*)(Bq + (size_t)i * NS);
    Bq += (size_t)8 * NS;
    fma_chunk(Aw, lda, kk, b0, acc);
    if (kk + 16 < KQ) {
#pragma unroll
      for (int i = 0; i < 8; i++) b0[i] = *(const float4*)(Bq + (size_t)i * NS);
      Bq += (size_t)8 * NS;
    }
    fma_chunk(Aw, lda, kk + 8, b1, acc);
  }
  if (KQ % 16 == 8) fma_chunk(Aw, lda, (KQ / 16) * 16, b0, acc);
}

// Cross-wave reduction of the 4 K-quarter partials via LDS.
// RED needs 12288 floats (48KB); may overlap the A tile (barrier-ordered).
// Wave w ends up owning final rows [4w, 4w+4) in fin[0..3] -> epilogue
// addressing is identical to the old per-wave-4-rows scheme.
// All register-array indices are compile-time (no scratch).
__device__ __forceinline__ void wave_reduce(const float4* acc, float4* fin,
                                            float* RED, int wid, int kl) {
  __syncthreads();  // all waves done reading the A tile
  float4* R4 = (float4*)RED;
#pragma unroll
  for (int r = 0; r < 16; r++) {
    int rg = r >> 2;
    if (rg != wid) {
      int r12 = r - (rg > wid ? 4 : 0);
      R4[(wid * 12 + r12) * 64 + kl] = acc[r];
    }
    if (rg == wid) fin[r & 3] = acc[r];
  }
  __syncthreads();
#pragma unroll
  for (int j = 0; j < 4; j++) {
    int r = wid * 4 + j;
#pragma unroll
    for (int w = 0; w < 4; w++) {
      if (w == wid) continue;
      int r12 = r - (wid > w ? 4 : 0);
      float4 v = R4[(w * 12 + r12) * 64 + kl];
      fin[j].x += v.x; fin[j].y += v.y; fin[j].z += v.z; fin[j].w += v.w;
    }
  }
}

// ===== Stage 1: code GEMM [0,176) | WkT [176,272) | LN [272,1552) ==========
__global__ __launch_bounds__(256, 2) void k_s1(
    const float* __restrict__ ss, const float* __restrict__ rs,
    const float* __restrict__ g_s, const float* __restrict__ b_s,
    const float* __restrict__ g_r, const float* __restrict__ b_r,
    const float* __restrict__ codes, const float* __restrict__ Wmq,
    const float* __restrict__ Wmk, const float* __restrict__ Wmv,
    const float* __restrict__ Wme, const float* __restrict__ Wk,
    float* __restrict__ s_ln, float* __restrict__ r_ln,
    float* __restrict__ cp, float* __restrict__ WkT) {
  __shared__ float SB[12288];
  int bid = blockIdx.x, t = threadIdx.x;
  if (bid < 176) {  // ---- code GEMM: 16 rows x 256 cols, K=384 (96/wave) ----
    int nc = bid % 11, mb = bid / 11;
    int base = nc * 256;
    const float* W; int N, colW;
    if (base < 768)       { W = Wmq; N = DD;    colW = base; }
    else if (base < 1536) { W = Wmk; N = DD;    colW = base - 768; }
    else if (base < 2304) { W = Wmv; N = DD;    colW = base - 1536; }
    else                  { W = Wme; N = INNER; colW = base - 2304; }
    int m0 = mb * 16;
#pragma unroll
    for (int p = 0; p < 24; p++) {
      int idx = p * 256 + t, r = idx / 384, k = idx % 384;
      SB[idx] = codes[(size_t)(m0 + r) * CDIM + k];
    }
    __syncthreads();
    int kl = t & 63, wid = t >> 6;
    float4 acc[16] = {};
    const float* Aw = SB + wid * 96;
    if (N == DD)
      gcore16<96, DD>(Aw, 384, W + (size_t)(wid * 96) * DD + colW + 4 * kl, acc);
    else
      gcore16<96, INNER>(Aw, 384, W + (size_t)(wid * 96) * INNER + colW + 4 * kl, acc);
    float4 fin[4];
    wave_reduce(acc, fin, SB, wid, kl);
    int m = m0 + wid * 4, gcol = base + 4 * kl;
#pragma unroll
    for (int j = 0; j < 4; j++)
      *(float4*)(cp + (size_t)(m + j) * 2816 + gcol) = fin[j];
  } else if (bid < 272) {  // ---- Wk transpose ----
    int tid = bid - 176;
    int d0 = (tid >> 3) * 64, c0 = (tid & 7) * 64;
    int j = t & 63, i0 = t >> 6;
#pragma unroll
    for (int p = 0; p < 16; p++) {
      int i = p * 4 + i0;
      SB[i * 65 + j] = Wk[(size_t)(d0 + i) * INNER + c0 + j];
    }
    __syncthreads();
#pragma unroll
    for (int p = 0; p < 16; p++) {
      int i = p * 4 + i0;
      WkT[(size_t)(c0 + i) * DD + d0 + j] = SB[j * 65 + i];
    }
  } else {  // ---- LayerNorm ----
    int rr = bid - 272;
    const float *x, *g, *bb; float* y; int r;
    if (rr < 1024) { x = ss; g = g_s; bb = b_s; y = s_ln; r = rr; }
    else           { x = rs; g = g_r; bb = b_r; y = r_ln; r = rr - 1024; }
    const float* xr = x + (size_t)r * DD;
    float v0 = xr[t], v1 = xr[t + 256], v2 = xr[t + 512];
    float s = v0 + v1 + v2, sq = v0 * v0 + v1 * v1 + v2 * v2;
    for (int o = 32; o > 0; o >>= 1) {
      s += __shfl_down(s, o, 64); sq += __shfl_down(sq, o, 64);
    }
    int wid = t >> 6, lane = t & 63;
    if (lane == 0) { SB[wid] = s; SB[wid + 4] = sq; }
    __syncthreads();
    float sum = SB[0] + SB[1] + SB[2] + SB[3];
    float ssq = SB[4] + SB[5] + SB[6] + SB[7];
    float mu = sum * (1.0f / 768.0f);
    float var = ssq * (1.0f / 768.0f) - mu * mu;
    float rstd = rsqrtf(var + 1e-5f);
    float* yr = y + (size_t)r * DD;
    yr[t]       = (v0 - mu) * rstd * g[t]       + bb[t];
    yr[t + 256] = (v1 - mu) * rstd * g[t + 256] + bb[t + 256];
    yr[t + 512] = (v2 - mu) * rstd * g[t + 512] + bb[t + 512];
  }
}

// ===== Stage 2: q partial [0,128) (Kc=192, 48/wave) | sT [128,320) =========
__global__ __launch_bounds__(256, 2) void k_s2(
    const float* __restrict__ s_ln, const float* __restrict__ r_ln,
    const float* __restrict__ cp, const float* __restrict__ Wq,
    float* __restrict__ sT, float* __restrict__ qp) {
  __shared__ float SB[12288];
  int bid = blockIdx.x, t = threadIdx.x;
  if (bid < 128) {
    int ks = bid & 3, tile = bid >> 2, nc = tile & 1, mb = tile >> 1;
    int m0 = mb * 16, col0 = nc * 256, k0 = ks * 192;
#pragma unroll
    for (int p = 0; p < 12; p++) {
      int idx = p * 256 + t, r = idx / 192, k = idx % 192;
      int d = k0 + k;
      float mqv = cp[(size_t)(m0 + r) * 2816 + d] + 1.0f;
      SB[idx] = r_ln[(size_t)(m0 + r) * DD + d] * mqv;
    }
    __syncthreads();
    int kl = t & 63, wid = t >> 6;
    int col = col0 + 4 * kl;
    float4 acc[16] = {};
    gcore16<48, INNER>(SB + wid * 48, 192,
                       Wq + (size_t)(k0 + wid * 48) * INNER + col, acc);
    float4 fin[4];
    wave_reduce(acc, fin, SB, wid, kl);
    int m = m0 + wid * 4;
    float* dst = qp + (size_t)ks * (256 * INNER);
#pragma unroll
    for (int j = 0; j < 4; j++)
      *(float4*)(dst + (size_t)(m + j) * INNER + col) = fin[j];
  } else {  // ---- sT[b][d][v] ----
    int tid = bid - 128;
    int vt = tid & 3, dt = (tid >> 2) % 12, b = tid / 48;
    int v0 = vt * 64, d0 = dt * 64;
    int j = t & 63, i0 = t >> 6;
#pragma unroll
    for (int p = 0; p < 16; p++) {
      int i = p * 4 + i0;
      SB[i * 65 + j] = s_ln[(size_t)(b * VV + v0 + i) * DD + d0 + j];
    }
    __syncthreads();
#pragma unroll
    for (int p = 0; p < 16; p++) {
      int i = p * 4 + i0;
      sT[((size_t)b * DD + d0 + i) * VV + v0 + j] = SB[j * 65 + i];
    }
  }
}

// ===== Stage 3: qmk [0,384) (K=64, 16/wave) | qbk [384,640) ================
__global__ __launch_bounds__(256, 2) void k_s3(
    const float* __restrict__ qp, const float* __restrict__ bq,
    const float* __restrict__ WkT, const float* __restrict__ cp,
    const float* __restrict__ bk, float* __restrict__ qm,
    float* __restrict__ qbk) {
  __shared__ float SB[12288];
  int bid = blockIdx.x, t = threadIdx.x;
  if (bid < 384) {
    int h = bid & 7, dc = (bid >> 3) % 3, mb = bid / 24;
    int m0 = mb * 16;
#pragma unroll
    for (int p = 0; p < 4; p++) {
      int idx = p * 256 + t, r = idx >> 6, c = idx & 63;
      int i = h * HD + c;
      size_t off = (size_t)(m0 + r) * INNER + i;
      SB[idx] = qp[off] + qp[131072 + off] + qp[262144 + off] +
                qp[393216 + off] + bq[i];
    }
    __syncthreads();
    int kl = t & 63, wid = t >> 6;
    int col = dc * 256 + 4 * kl;
    float4 acc[16] = {};
    gcore16<16, DD>(SB + wid * 16, HD,
                    WkT + (size_t)(h * HD + wid * 16) * DD + col, acc);
    float4 fin[4];
    wave_reduce(acc, fin, SB, wid, kl);
#pragma unroll
    for (int j = 0; j < 4; j++) {
      int m = m0 + wid * 4 + j;
      const float* mkp = cp + (size_t)m * 2816 + 768 + col;
      float4 o = {fin[j].x * (mkp[0] + 1.0f), fin[j].y * (mkp[1] + 1.0f),
                  fin[j].z * (mkp[2] + 1.0f), fin[j].w * (mkp[3] + 1.0f)};
      *(float4*)(qm + ((size_t)m * NH + h) * DD + col) = o;
    }
  } else {  // ---- qbk ----
    int m = bid - 384;
    size_t off = (size_t)m * INNER;
    SB[t] = (qp[off + t] + qp[131072 + off + t] + qp[262144 + off + t] +
             qp[393216 + off + t] + bq[t]) * bk[t];
    int t2 = t + 256;
    SB[t2] = (qp[off + t2] + qp[131072 + off + t2] + qp[262144 + off + t2] +
              qp[393216 + off + t2] + bq[t2]) * bk[t2];
    __syncthreads();
    if (t < 8) {
      float a = 0.f;
      for (int c = 0; c < HD; c++) a += SB[t * HD + c];
      qbk[m * NH + t] = a;
    }
  }
}

// ===== Stage 4: scores partial (512 blocks, Kc=192, 48/wave) ===============
__global__ __launch_bounds__(256, 2) void k_s4(
    const float* __restrict__ qm, const float* __restrict__ sT,
    float* __restrict__ scp) {
  __shared__ float SB[12288];
  int bid = blockIdx.x, t = threadIdx.x;
  int ks = bid & 3, b = (bid >> 2) & 3, mb = bid >> 4;
  int gi0 = b * 512 + mb * 16, k0 = ks * 192;
#pragma unroll
  for (int p = 0; p < 12; p++) {
    int idx = p * 256 + t, r = idx / 192, k = idx % 192;
    SB[idx] = qm[(size_t)(gi0 + r) * DD + k0 + k];
  }
  __syncthreads();
  int kl = t & 63, wid = t >> 6;
  int col = 4 * kl;
  float4 acc[16] = {};
  gcore16<48, VV>(SB + wid * 48, 192,
                  sT + ((size_t)b * DD + k0 + wid * 48) * VV + col, acc);
  float4 fin[4];
  wave_reduce(acc, fin, SB, wid, kl);
  int gi = gi0 + wid * 4;
  float* dst = scp + (size_t)ks * (2048 * VV);
#pragma unroll
  for (int j = 0; j < 4; j++)
    *(float4*)(dst + (size_t)(gi + j) * VV + col) = fin[j];
}

// ===== Stage 5: softmax + ws GEMM (384 blocks, K=256, 64/wave) =============
__global__ __launch_bounds__(256, 2) void k_s5(
    const float* __restrict__ scp, const float* __restrict__ qbk,
    const float* __restrict__ s_ln, const float* __restrict__ cp,
    float* __restrict__ wsm) {
  __shared__ float SC[12288];
  int bid = blockIdx.x, t = threadIdx.x;
  int dc = bid % 3, up = (bid / 3) % 32, b = bid / 96;
  int gi0 = b * 512 + up * 16;
#pragma unroll
  for (int p = 0; p < 16; p++) {
    int idx = p * 256 + t, r = idx >> 8, c = idx & 255;
    size_t o = (size_t)(gi0 + r) * VV + c;
    float v = scp[o] + scp[524288 + o] + scp[1048576 + o] + scp[1572864 + o];
    int m = b * 64 + up * 2 + (r >> 3), h = r & 7;
    SC[idx] = (v + qbk[m * NH + h]) * 0.125f;
  }
  __syncthreads();
  int wid = t >> 6, lane = t & 63;
#pragma unroll
  for (int j = 0; j < 4; j++) {
    int r = wid * 4 + j;
    float x0 = SC[r * 256 + lane],       x1 = SC[r * 256 + lane + 64];
    float x2 = SC[r * 256 + lane + 128], x3 = SC[r * 256 + lane + 192];
    float mx = fmaxf(fmaxf(x0, x1), fmaxf(x2, x3));
    for (int o = 1; o < 64; o <<= 1) mx = fmaxf(mx, __shfl_xor(mx, o, 64));
    float e0 = __expf(x0 - mx), e1 = __expf(x1 - mx);
    float e2 = __expf(x2 - mx), e3 = __expf(x3 - mx);
    float sm = e0 + e1 + e2 + e3;
    for (int o = 1; o < 64; o <<= 1) sm += __shfl_xor(sm, o, 64);
    float rinv = 1.0f / sm;
    SC[r * 256 + lane] = e0 * rinv;       SC[r * 256 + lane + 64] = e1 * rinv;
    SC[r * 256 + lane + 128] = e2 * rinv; SC[r * 256 + lane + 192] = e3 * rinv;
  }
  __syncthreads();
  int kl = t & 63;
  int col = dc * 256 + 4 * kl;
  float4 acc[16] = {};
  gcore16<64, DD>(SC + wid * 64, 256,
                  s_ln + (size_t)(b * VV + wid * 64) * DD + col, acc);
  float4 fin[4];
  wave_reduce(acc, fin, SC, wid, kl);
#pragma unroll
  for (int j = 0; j < 4; j++) {
    int r = wid * 4 + j;
    int ul = r >> 3, h = r & 7, m = b * 64 + up * 2 + ul;
    const float* mvp = cp + (size_t)m * 2816 + 1536 + col;
    float4 o = {fin[j].x * (mvp[0] + 1.0f), fin[j].y * (mvp[1] + 1.0f),
                fin[j].z * (mvp[2] + 1.0f), fin[j].w * (mvp[3] + 1.0f)};
    *(float4*)(wsm + ((size_t)h * 256 + m) * DD + col) = o;
  }
}

// ===== Stage 6: msg partial (256 blocks, Kc=96, 24/wave) ===================
__global__ __launch_bounds__(256, 2) void k_s6(
    const float* __restrict__ wsm, const float* __restrict__ Wv,
    float* __restrict__ mmp) {
  __shared__ float AL[12288];
  int bid = blockIdx.x, t = threadIdx.x;
  int hp = bid & 1, ks = (bid >> 1) & 7, mb = bid >> 4;
  int h0 = hp * 4, m0 = mb * 16, k0 = ks * 96;
#pragma unroll
  for (int p = 0; p < 24; p++) {
    int idx = p * 256 + t;
    int e = idx / 1536, rem = idx % 1536, r = rem / 96, k = rem % 96;
    AL[idx] = wsm[((size_t)(h0 + e) * 256 + m0 + r) * DD + k0 + k];
  }
  __syncthreads();
  int kl = t & 63, wid = t >> 6;
  int hs = kl >> 4, c4 = 4 * (kl & 15);
  int colg = h0 * HD + hs * HD + c4;
  const float* Aw = AL + hs * 1536 + wid * 24;
  float4 acc[16] = {};
  gcore16<24, INNER>(Aw, 96, Wv + (size_t)(k0 + wid * 24) * INNER + colg, acc);
  float4 fin[4];
  wave_reduce(acc, fin, AL, wid, kl);
  float* dst = mmp + (size_t)ks * (256 * INNER);
  int m = m0 + wid * 4;
#pragma unroll
  for (int j = 0; j < 4; j++)
    *(float4*)(dst + (size_t)(m + j) * INNER + colg) = fin[j];
}

// ===== Stage 7: out partial (384 blocks, Kc=64, 16/wave) ===================
__global__ __launch_bounds__(256, 2) void k_s7(
    const float* __restrict__ mmp, const float* __restrict__ bvv,
    const float* __restrict__ cp, const float* __restrict__ We,
    float* __restrict__ op) {
  __shared__ float AL[12288];
  int bid = blockIdx.x, t = threadIdx.x;
  int ks = bid & 7, dc = (bid >> 3) % 3, mb = bid / 24;
  int m0 = mb * 16, k0 = ks * 64;
#pragma unroll
  for (int p = 0; p < 4; p++) {
    int idx = p * 256 + t, r = idx >> 6, k = idx & 63;
    int i = k0 + k;
    size_t off = (size_t)(m0 + r) * INNER + i;
    float v = mmp[off] + mmp[131072 + off] + mmp[262144 + off] +
              mmp[393216 + off] + mmp[524288 + off] + mmp[655360 + off] +
              mmp[786432 + off] + mmp[917504 + off];
    float mev = cp[(size_t)(m0 + r) * 2816 + 2304 + i] + 1.0f;
    AL[idx] = (v + bvv[i]) * mev;
  }
  __syncthreads();
  int kl = t & 63, wid = t >> 6;
  int col = dc * 256 + 4 * kl;
  float4 acc[16] = {};
  gcore16<16, DD>(AL + wid * 16, 64,
                  We + (size_t)(k0 + wid * 16) * DD + col, acc);
  float4 fin[4];
  wave_reduce(acc, fin, AL, wid, kl);
  float* dst = op + (size_t)ks * (256 * DD);
  int m = m0 + wid * 4;
#pragma unroll
  for (int j = 0; j < 4; j++)
    *(float4*)(dst + (size_t)(m + j) * DD + col) = fin[j];
}

// ===== Stage 8: epilogue (256 blocks) ======================================
__global__ __launch_bounds__(256) void k_s8(
    const float* __restrict__ op, const float* __restrict__ be,
    const float* __restrict__ gamma, const float* __restrict__ rs,
    float* __restrict__ outp) {
  int m = blockIdx.x, t = threadIdx.x;
#pragma unroll
  for (int j = 0; j < 3; j++) {
    int d = t + j * 256;
    size_t off = (size_t)m * DD + d;
    float v = op[off] + op[196608 + off] + op[393216 + off] +
              op[589824 + off] + op[786432 + off] + op[983040 + off] +
              op[1179648 + off] + op[1376256 + off];
    outp[off] = rs[off] + (v + be[d]) * gamma[d];
  }
}

extern "C" void kernel_launch(void* const* d_in, const int* in_sizes, int n_in,
                              void* d_out, int out_size, void* d_ws, size_t ws_size,
                              hipStream_t stream) {
  const float* rs     = (const float*)d_in[0];
  const float* codes  = (const float*)d_in[1];
  const float* ss     = (const float*)d_in[2];
  const float* ln_r_g = (const float*)d_in[3];
  const float* ln_r_b = (const float*)d_in[4];
  const float* ln_s_g = (const float*)d_in[5];
  const float* ln_s_b = (const float*)d_in[6];
  const float* Wq  = (const float*)d_in[7];
  const float* bq  = (const float*)d_in[8];
  const float* Wk  = (const float*)d_in[10];
  const float* bk  = (const float*)d_in[11];
  const float* Wmq = (const float*)d_in[9];
  const float* Wmk = (const float*)d_in[12];
  const float* Wv  = (const float*)d_in[13];
  const float* bv  = (const float*)d_in[14];
  const float* Wmv = (const float*)d_in[15];
  const float* We  = (const float*)d_in[16];
  const float* be  = (const float*)d_in[17];
  const float* Wme = (const float*)d_in[18];
  const float* gamma = (const float*)d_in[19];

  float* w = (float*)d_ws;
  // liveness-aliased layout (float offsets); peak ≈ 28.3 MB
  float* s_ln = w;                  // @0        786432  (s1 -> s5)
  float* r_ln = w + 786432;         //           196608  (s1 -> s2)
  float* WkT  = w + 983040;         //           393216  (s1 -> s3)
  float* qp   = w + 1376256;        //           524288  (s2 -> s3, 4 partials)
  float* sT   = w + 1900544;        //           786432  (s2 -> s4)
  float* cp   = w + 2686976;        //           720896  (s1 -> s7) [m][2816]
  float* qbk  = w + 3407872;        //             2048  (s3 -> s5)
  float* qm   = w + 3409920;        //          1572864  (s3 -> s4)
  float* scp  = w + 4982784;        //          2097152  (s4 -> s5, 4 partials)
  float* wsm  = qm;                 // alias (s5 -> s6)
  float* mmp  = r_ln;               // alias r_ln+WkT+qp region (s6 -> s7, 8 partials)
  float* op   = scp;                // alias (s7 -> s8, 8 partials)

  k_s1<<<dim3(1552), 256, 0, stream>>>(ss, rs, ln_s_g, ln_s_b, ln_r_g, ln_r_b,
                                       codes, Wmq, Wmk, Wmv, Wme, Wk,
                                       s_ln, r_ln, cp, WkT);
  k_s2<<<dim3(320), 256, 0, stream>>>(s_ln, r_ln, cp, Wq, sT, qp);
  k_s3<<<dim3(640), 256, 0, stream>>>(qp, bq, WkT, cp, bk, qm, qbk);
  k_s4<<<dim3(512), 256, 0, stream>>>(qm, sT, scp);
  k_s5<<<dim3(384), 256, 0, stream>>>(scp, qbk, s_ln, cp, wsm);
  k_s6<<<dim3(256), 256, 0, stream>>>(wsm, Wv, mmp);
  k_s7<<<dim3(384), 256, 0, stream>>>(mmp, bv, cp, We, op);
  k_s8<<<dim3(256), 256, 0, stream>>>(op, be, gamma, rs, (float*)d_out);
}

// Round 2
// 186.873 us; speedup vs baseline: 1.5900x; 1.5900x over previous
//
#include <hip/hip_runtime.h>

// ReadInAttention — 8-stage f32 pipeline.
// v3 gcore: 2-way K-split x 2-way row-split per block (wave w: rows
// (w&1)*8..+8, K-half w>>1). Halves B-bytes-per-FLOP vs v1 (B panel read
// by 2 waves instead of 4) at unchanged per-block VALU time and grid.
// acc[8] (32 VGPR) keeps register pressure spill-free. Cross-K-half
// reduce via 16KB LDS round-trip (overlaps A tile, barrier-ordered).
// Dual 8-deep float4 B prefetch; A broadcast via float4 (ds_read_b128).

#define DD 768
#define CDIM 384
#define NH 8
#define HD 64
#define INNER 512
#define VV 256

__device__ __forceinline__ void fma4(float4& a, float s, const float4& b) {
  a.x += s * b.x; a.y += s * b.y; a.z += s * b.z; a.w += s * b.w;
}

// 8 rows x 8 k FMA block. A fragments as float4 pairs (2 rows at a time).
__device__ __forceinline__ void fma_chunk8(const float* __restrict__ Aw,
                                           int lda, int kk, const float4* b,
                                           float4* acc) {
#pragma unroll
  for (int rg = 0; rg < 4; rg++) {
    const float* ap = Aw + (rg * 2) * lda + kk;
    float4 a0l = *(const float4*)(ap);
    float4 a0h = *(const float4*)(ap + 4);
    float4 a1l = *(const float4*)(ap + lda);
    float4 a1h = *(const float4*)(ap + lda + 4);
    float4* ac = acc + rg * 2;
    fma4(ac[0], a0l.x, b[0]); fma4(ac[1], a1l.x, b[0]);
    fma4(ac[0], a0l.y, b[1]); fma4(ac[1], a1l.y, b[1]);
    fma4(ac[0], a0l.z, b[2]); fma4(ac[1], a1l.z, b[2]);
    fma4(ac[0], a0l.w, b[3]); fma4(ac[1], a1l.w, b[3]);
    fma4(ac[0], a0h.x, b[4]); fma4(ac[1], a1h.x, b[4]);
    fma4(ac[0], a0h.y, b[5]); fma4(ac[1], a1h.y, b[5]);
    fma4(ac[0], a0h.z, b[6]); fma4(ac[1], a1h.z, b[6]);
    fma4(ac[0], a0h.w, b[7]); fma4(ac[1], a1h.w, b[7]);
  }
}

// Per-wave GEMM over a K-half: 8 rows x (64 lanes * float4) cols.
// KQ = K/2, multiple of 16. Aw/Bp pre-offset to this wave's rows/K-half.
template <int KQ, int NS>
__device__ __forceinline__ void gcore8(const float* __restrict__ Aw, int lda,
                                       const float* __restrict__ Bp,
                                       float4* acc) {
  float4 b0[8], b1[8];
  const float* Bq = Bp;
#pragma unroll
  for (int i = 0; i < 8; i++) b0[i] = *(const float4*)(Bq + (size_t)i * NS);
  Bq += (size_t)8 * NS;
#pragma unroll 1
  for (int kk = 0; kk + 16 <= KQ; kk += 16) {
#pragma unroll
    for (int i = 0; i < 8; i++) b1[i] = *(const float4*)(Bq + (size_t)i * NS);
    Bq += (size_t)8 * NS;
    fma_chunk8(Aw, lda, kk, b0, acc);
    if (kk + 16 < KQ) {
#pragma unroll
      for (int i = 0; i < 8; i++) b0[i] = *(const float4*)(Bq + (size_t)i * NS);
      Bq += (size_t)8 * NS;
    }
    fma_chunk8(Aw, lda, kk + 8, b1, acc);
  }
}

// Cross-K-half reduce. Waves kh==1 dump acc (16KB) to RED; kh==0 waves add.
// After this, wave 0 holds final rows 0-7, wave 1 rows 8-15; waves 2,3 done.
// RED may overlap the A tile (first barrier orders all A reads before it).
__device__ __forceinline__ void kred(float4* acc, float* RED, int wid,
                                     int kl) {
  __syncthreads();
  float4* R4 = (float4*)RED;
  int rg = wid & 1, kh = wid >> 1;
  if (kh) {
#pragma unroll
    for (int r = 0; r < 8; r++) R4[(rg * 8 + r) * 64 + kl] = acc[r];
  }
  __syncthreads();
  if (!kh) {
#pragma unroll
    for (int r = 0; r < 8; r++) {
      float4 v = R4[(rg * 8 + r) * 64 + kl];
      acc[r].x += v.x; acc[r].y += v.y; acc[r].z += v.z; acc[r].w += v.w;
    }
  }
}

// ===== Stage 1: code GEMM [0,176) | WkT [176,272) | LN [272,1552) ==========
__global__ __launch_bounds__(256, 2) void k_s1(
    const float* __restrict__ ss, const float* __restrict__ rs,
    const float* __restrict__ g_s, const float* __restrict__ b_s,
    const float* __restrict__ g_r, const float* __restrict__ b_r,
    const float* __restrict__ codes, const float* __restrict__ Wmq,
    const float* __restrict__ Wmk, const float* __restrict__ Wmv,
    const float* __restrict__ Wme, const float* __restrict__ Wk,
    float* __restrict__ s_ln, float* __restrict__ r_ln,
    float* __restrict__ cp, float* __restrict__ WkT) {
  __shared__ __align__(16) float SB[6144];
  int bid = blockIdx.x, t = threadIdx.x;
  if (bid < 176) {  // ---- code GEMM: 16 rows x 256 cols, K=384 (192/half) --
    int nc = bid % 11, mb = bid / 11;
    int base = nc * 256;
    const float* W; int N, colW;
    if (base < 768)       { W = Wmq; N = DD;    colW = base; }
    else if (base < 1536) { W = Wmk; N = DD;    colW = base - 768; }
    else if (base < 2304) { W = Wmv; N = DD;    colW = base - 1536; }
    else                  { W = Wme; N = INNER; colW = base - 2304; }
    int m0 = mb * 16;
#pragma unroll
    for (int p = 0; p < 24; p++) {
      int idx = p * 256 + t, r = idx / 384, k = idx % 384;
      SB[idx] = codes[(size_t)(m0 + r) * CDIM + k];
    }
    __syncthreads();
    int kl = t & 63, wid = t >> 6, rg = wid & 1, kh = wid >> 1;
    float4 acc[8] = {};
    const float* Aw = SB + (rg * 8) * 384 + kh * 192;
    if (N == DD)
      gcore8<192, DD>(Aw, 384, W + (size_t)(kh * 192) * DD + colW + 4 * kl, acc);
    else
      gcore8<192, INNER>(Aw, 384, W + (size_t)(kh * 192) * INNER + colW + 4 * kl, acc);
    kred(acc, SB, wid, kl);
    if (!kh) {
      int gcol = base + 4 * kl;
#pragma unroll
      for (int j = 0; j < 8; j++)
        *(float4*)(cp + (size_t)(m0 + rg * 8 + j) * 2816 + gcol) = acc[j];
    }
  } else if (bid < 272) {  // ---- Wk transpose ----
    int tid = bid - 176;
    int d0 = (tid >> 3) * 64, c0 = (tid & 7) * 64;
    int j = t & 63, i0 = t >> 6;
#pragma unroll
    for (int p = 0; p < 16; p++) {
      int i = p * 4 + i0;
      SB[i * 65 + j] = Wk[(size_t)(d0 + i) * INNER + c0 + j];
    }
    __syncthreads();
#pragma unroll
    for (int p = 0; p < 16; p++) {
      int i = p * 4 + i0;
      WkT[(size_t)(c0 + i) * DD + d0 + j] = SB[j * 65 + i];
    }
  } else {  // ---- LayerNorm ----
    int rr = bid - 272;
    const float *x, *g, *bb; float* y; int r;
    if (rr < 1024) { x = ss; g = g_s; bb = b_s; y = s_ln; r = rr; }
    else           { x = rs; g = g_r; bb = b_r; y = r_ln; r = rr - 1024; }
    const float* xr = x + (size_t)r * DD;
    float v0 = xr[t], v1 = xr[t + 256], v2 = xr[t + 512];
    float s = v0 + v1 + v2, sq = v0 * v0 + v1 * v1 + v2 * v2;
    for (int o = 32; o > 0; o >>= 1) {
      s += __shfl_down(s, o, 64); sq += __shfl_down(sq, o, 64);
    }
    int wid = t >> 6, lane = t & 63;
    if (lane == 0) { SB[wid] = s; SB[wid + 4] = sq; }
    __syncthreads();
    float sum = SB[0] + SB[1] + SB[2] + SB[3];
    float ssq = SB[4] + SB[5] + SB[6] + SB[7];
    float mu = sum * (1.0f / 768.0f);
    float var = ssq * (1.0f / 768.0f) - mu * mu;
    float rstd = rsqrtf(var + 1e-5f);
    float* yr = y + (size_t)r * DD;
    yr[t]       = (v0 - mu) * rstd * g[t]       + bb[t];
    yr[t + 256] = (v1 - mu) * rstd * g[t + 256] + bb[t + 256];
    yr[t + 512] = (v2 - mu) * rstd * g[t + 512] + bb[t + 512];
  }
}

// ===== Stage 2: q partial [0,128) (Kc=192, 96/half) | sT [128,320) =========
__global__ __launch_bounds__(256, 2) void k_s2(
    const float* __restrict__ s_ln, const float* __restrict__ r_ln,
    const float* __restrict__ cp, const float* __restrict__ Wq,
    float* __restrict__ sT, float* __restrict__ qp) {
  __shared__ __align__(16) float SB[4160];
  int bid = blockIdx.x, t = threadIdx.x;
  if (bid < 128) {
    int ks = bid & 3, tile = bid >> 2, nc = tile & 1, mb = tile >> 1;
    int m0 = mb * 16, col0 = nc * 256, k0 = ks * 192;
#pragma unroll
    for (int p = 0; p < 12; p++) {
      int idx = p * 256 + t, r = idx / 192, k = idx % 192;
      int d = k0 + k;
      float mqv = cp[(size_t)(m0 + r) * 2816 + d] + 1.0f;
      SB[idx] = r_ln[(size_t)(m0 + r) * DD + d] * mqv;
    }
    __syncthreads();
    int kl = t & 63, wid = t >> 6, rg = wid & 1, kh = wid >> 1;
    int col = col0 + 4 * kl;
    float4 acc[8] = {};
    gcore8<96, INNER>(SB + (rg * 8) * 192 + kh * 96, 192,
                      Wq + (size_t)(k0 + kh * 96) * INNER + col, acc);
    kred(acc, SB, wid, kl);
    if (!kh) {
      float* dst = qp + (size_t)ks * (256 * INNER);
#pragma unroll
      for (int j = 0; j < 8; j++)
        *(float4*)(dst + (size_t)(m0 + rg * 8 + j) * INNER + col) = acc[j];
    }
  } else {  // ---- sT[b][d][v] ----
    int tid = bid - 128;
    int vt = tid & 3, dt = (tid >> 2) % 12, b = tid / 48;
    int v0 = vt * 64, d0 = dt * 64;
    int j = t & 63, i0 = t >> 6;
#pragma unroll
    for (int p = 0; p < 16; p++) {
      int i = p * 4 + i0;
      SB[i * 65 + j] = s_ln[(size_t)(b * VV + v0 + i) * DD + d0 + j];
    }
    __syncthreads();
#pragma unroll
    for (int p = 0; p < 16; p++) {
      int i = p * 4 + i0;
      sT[((size_t)b * DD + d0 + i) * VV + v0 + j] = SB[j * 65 + i];
    }
  }
}

// ===== Stage 3: qmk [0,384) (K=64, 32/half) | qbk [384,640) ================
__global__ __launch_bounds__(256, 2) void k_s3(
    const float* __restrict__ qp, const float* __restrict__ bq,
    const float* __restrict__ WkT, const float* __restrict__ cp,
    const float* __restrict__ bk, float* __restrict__ qm,
    float* __restrict__ qbk) {
  __shared__ __align__(16) float SB[4096];
  int bid = blockIdx.x, t = threadIdx.x;
  if (bid < 384) {
    int h = bid & 7, dc = (bid >> 3) % 3, mb = bid / 24;
    int m0 = mb * 16;
#pragma unroll
    for (int p = 0; p < 4; p++) {
      int idx = p * 256 + t, r = idx >> 6, c = idx & 63;
      int i = h * HD + c;
      size_t off = (size_t)(m0 + r) * INNER + i;
      SB[idx] = qp[off] + qp[131072 + off] + qp[262144 + off] +
                qp[393216 + off] + bq[i];
    }
    __syncthreads();
    int kl = t & 63, wid = t >> 6, rg = wid & 1, kh = wid >> 1;
    int col = dc * 256 + 4 * kl;
    float4 acc[8] = {};
    gcore8<32, DD>(SB + (rg * 8) * HD + kh * 32, HD,
                   WkT + (size_t)(h * HD + kh * 32) * DD + col, acc);
    kred(acc, SB, wid, kl);
    if (!kh) {
#pragma unroll
      for (int j = 0; j < 8; j++) {
        int m = m0 + rg * 8 + j;
        const float* mkp = cp + (size_t)m * 2816 + 768 + col;
        float4 o = {acc[j].x * (mkp[0] + 1.0f), acc[j].y * (mkp[1] + 1.0f),
                    acc[j].z * (mkp[2] + 1.0f), acc[j].w * (mkp[3] + 1.0f)};
        *(float4*)(qm + ((size_t)m * NH + h) * DD + col) = o;
      }
    }
  } else {  // ---- qbk ----
    int m = bid - 384;
    size_t off = (size_t)m * INNER;
    SB[t] = (qp[off + t] + qp[131072 + off + t] + qp[262144 + off + t] +
             qp[393216 + off + t] + bq[t]) * bk[t];
    int t2 = t + 256;
    SB[t2] = (qp[off + t2] + qp[131072 + off + t2] + qp[262144 + off + t2] +
              qp[393216 + off + t2] + bq[t2]) * bk[t2];
    __syncthreads();
    if (t < 8) {
      float a = 0.f;
      for (int c = 0; c < HD; c++) a += SB[t * HD + c];
      qbk[m * NH + t] = a;
    }
  }
}

// ===== Stage 4: scores partial (512 blocks, Kc=192, 96/half) ===============
__global__ __launch_bounds__(256, 2) void k_s4(
    const float* __restrict__ qm, const float* __restrict__ sT,
    float* __restrict__ scp) {
  __shared__ __align__(16) float SB[4096];
  int bid = blockIdx.x, t = threadIdx.x;
  int ks = bid & 3, b = (bid >> 2) & 3, mb = bid >> 4;
  int gi0 = b * 512 + mb * 16, k0 = ks * 192;
#pragma unroll
  for (int p = 0; p < 12; p++) {
    int idx = p * 256 + t, r = idx / 192, k = idx % 192;
    SB[idx] = qm[(size_t)(gi0 + r) * DD + k0 + k];
  }
  __syncthreads();
  int kl = t & 63, wid = t >> 6, rg = wid & 1, kh = wid >> 1;
  int col = 4 * kl;
  float4 acc[8] = {};
  gcore8<96, VV>(SB + (rg * 8) * 192 + kh * 96, 192,
                 sT + ((size_t)b * DD + k0 + kh * 96) * VV + col, acc);
  kred(acc, SB, wid, kl);
  if (!kh) {
    float* dst = scp + (size_t)ks * (2048 * VV);
#pragma unroll
    for (int j = 0; j < 8; j++)
      *(float4*)(dst + (size_t)(gi0 + rg * 8 + j) * VV + col) = acc[j];
  }
}

// ===== Stage 5: softmax + ws GEMM (384 blocks, K=256, 128/half) ============
__global__ __launch_bounds__(256, 2) void k_s5(
    const float* __restrict__ scp, const float* __restrict__ qbk,
    const float* __restrict__ s_ln, const float* __restrict__ cp,
    float* __restrict__ wsm) {
  __shared__ __align__(16) float SC[4096];
  int bid = blockIdx.x, t = threadIdx.x;
  int dc = bid % 3, up = (bid / 3) % 32, b = bid / 96;
  int gi0 = b * 512 + up * 16;
#pragma unroll
  for (int p = 0; p < 16; p++) {
    int idx = p * 256 + t, r = idx >> 8, c = idx & 255;
    size_t o = (size_t)(gi0 + r) * VV + c;
    float v = scp[o] + scp[524288 + o] + scp[1048576 + o] + scp[1572864 + o];
    int m = b * 64 + up * 2 + (r >> 3), h = r & 7;
    SC[idx] = (v + qbk[m * NH + h]) * 0.125f;
  }
  __syncthreads();
  int wid = t >> 6, lane = t & 63;
#pragma unroll
  for (int j = 0; j < 4; j++) {
    int r = wid * 4 + j;
    float x0 = SC[r * 256 + lane],       x1 = SC[r * 256 + lane + 64];
    float x2 = SC[r * 256 + lane + 128], x3 = SC[r * 256 + lane + 192];
    float mx = fmaxf(fmaxf(x0, x1), fmaxf(x2, x3));
    for (int o = 1; o < 64; o <<= 1) mx = fmaxf(mx, __shfl_xor(mx, o, 64));
    float e0 = __expf(x0 - mx), e1 = __expf(x1 - mx);
    float e2 = __expf(x2 - mx), e3 = __expf(x3 - mx);
    float sm = e0 + e1 + e2 + e3;
    for (int o = 1; o < 64; o <<= 1) sm += __shfl_xor(sm, o, 64);
    float rinv = 1.0f / sm;
    SC[r * 256 + lane] = e0 * rinv;       SC[r * 256 + lane + 64] = e1 * rinv;
    SC[r * 256 + lane + 128] = e2 * rinv; SC[r * 256 + lane + 192] = e3 * rinv;
  }
  __syncthreads();
  int kl = t & 63, rg = wid & 1, kh = wid >> 1;
  int col = dc * 256 + 4 * kl;
  float4 acc[8] = {};
  gcore8<128, DD>(SC + (rg * 8) * 256 + kh * 128, 256,
                  s_ln + (size_t)(b * VV + kh * 128) * DD + col, acc);
  kred(acc, SC, wid, kl);
  if (!kh) {
#pragma unroll
    for (int j = 0; j < 8; j++) {
      // row r = rg*8+j -> head j, u-slot rg
      int m = b * 64 + up * 2 + rg;
      const float* mvp = cp + (size_t)m * 2816 + 1536 + col;
      float4 o = {acc[j].x * (mvp[0] + 1.0f), acc[j].y * (mvp[1] + 1.0f),
                  acc[j].z * (mvp[2] + 1.0f), acc[j].w * (mvp[3] + 1.0f)};
      *(float4*)(wsm + ((size_t)j * 256 + m) * DD + col) = o;
    }
  }
}

// ===== Stage 6: msg partial (256 blocks, Kc=96, 48/half) ===================
__global__ __launch_bounds__(256, 2) void k_s6(
    const float* __restrict__ wsm, const float* __restrict__ Wv,
    float* __restrict__ mmp) {
  __shared__ __align__(16) float AL[6144];
  int bid = blockIdx.x, t = threadIdx.x;
  int hp = bid & 1, ks = (bid >> 1) & 7, mb = bid >> 4;
  int h0 = hp * 4, m0 = mb * 16, k0 = ks * 96;
#pragma unroll
  for (int p = 0; p < 24; p++) {
    int idx = p * 256 + t;
    int e = idx / 1536, rem = idx % 1536, r = rem / 96, k = rem % 96;
    AL[idx] = wsm[((size_t)(h0 + e) * 256 + m0 + r) * DD + k0 + k];
  }
  __syncthreads();
  int kl = t & 63, wid = t >> 6, rg = wid & 1, kh = wid >> 1;
  int hs = kl >> 4, c4 = 4 * (kl & 15);
  int colg = h0 * HD + hs * HD + c4;
  const float* Aw = AL + hs * 1536 + (rg * 8) * 96 + kh * 48;
  float4 acc[8] = {};
  gcore8<48, INNER>(Aw, 96, Wv + (size_t)(k0 + kh * 48) * INNER + colg, acc);
  kred(acc, AL, wid, kl);
  if (!kh) {
    float* dst = mmp + (size_t)ks * (256 * INNER);
#pragma unroll
    for (int j = 0; j < 8; j++)
      *(float4*)(dst + (size_t)(m0 + rg * 8 + j) * INNER + colg) = acc[j];
  }
}

// ===== Stage 7: out partial (384 blocks, Kc=64, 32/half) ===================
__global__ __launch_bounds__(256, 2) void k_s7(
    const float* __restrict__ mmp, const float* __restrict__ bvv,
    const float* __restrict__ cp, const float* __restrict__ We,
    float* __restrict__ op) {
  __shared__ __align__(16) float AL[4096];
  int bid = blockIdx.x, t = threadIdx.x;
  int ks = bid & 7, dc = (bid >> 3) % 3, mb = bid / 24;
  int m0 = mb * 16, k0 = ks * 64;
#pragma unroll
  for (int p = 0; p < 4; p++) {
    int idx = p * 256 + t, r = idx >> 6, k = idx & 63;
    int i = k0 + k;
    size_t off = (size_t)(m0 + r) * INNER + i;
    float v = mmp[off] + mmp[131072 + off] + mmp[262144 + off] +
              mmp[393216 + off] + mmp[524288 + off] + mmp[655360 + off] +
              mmp[786432 + off] + mmp[917504 + off];
    float mev = cp[(size_t)(m0 + r) * 2816 + 2304 + i] + 1.0f;
    AL[idx] = (v + bvv[i]) * mev;
  }
  __syncthreads();
  int kl = t & 63, wid = t >> 6, rg = wid & 1, kh = wid >> 1;
  int col = dc * 256 + 4 * kl;
  float4 acc[8] = {};
  gcore8<32, DD>(AL + (rg * 8) * 64 + kh * 32, 64,
                 We + (size_t)(k0 + kh * 32) * DD + col, acc);
  kred(acc, AL, wid, kl);
  if (!kh) {
    float* dst = op + (size_t)ks * (256 * DD);
#pragma unroll
    for (int j = 0; j < 8; j++)
      *(float4*)(dst + (size_t)(m0 + rg * 8 + j) * DD + col) = acc[j];
  }
}

// ===== Stage 8: epilogue (256 blocks) ======================================
__global__ __launch_bounds__(256) void k_s8(
    const float* __restrict__ op, const float* __restrict__ be,
    const float* __restrict__ gamma, const float* __restrict__ rs,
    float* __restrict__ outp) {
  int m = blockIdx.x, t = threadIdx.x;
#pragma unroll
  for (int j = 0; j < 3; j++) {
    int d = t + j * 256;
    size_t off = (size_t)m * DD + d;
    float v = op[off] + op[196608 + off] + op[393216 + off] +
              op[589824 + off] + op[786432 + off] + op[983040 + off] +
              op[1179648 + off] + op[1376256 + off];
    outp[off] = rs[off] + (v + be[d]) * gamma[d];
  }
}

extern "C" void kernel_launch(void* const* d_in, const int* in_sizes, int n_in,
                              void* d_out, int out_size, void* d_ws, size_t ws_size,
                              hipStream_t stream) {
  const float* rs     = (const float*)d_in[0];
  const float* codes  = (const float*)d_in[1];
  const float* ss     = (const float*)d_in[2];
  const float* ln_r_g = (const float*)d_in[3];
  const float* ln_r_b = (const float*)d_in[4];
  const float* ln_s_g = (const float*)d_in[5];
  const float* ln_s_b = (const float*)d_in[6];
  const float* Wq  = (const float*)d_in[7];
  const float* bq  = (const float*)d_in[8];
  const float* Wk  = (const float*)d_in[10];
  const float* bk  = (const float*)d_in[11];
  const float* Wmq = (const float*)d_in[9];
  const float* Wmk = (const float*)d_in[12];
  const float* Wv  = (const float*)d_in[13];
  const float* bv  = (const float*)d_in[14];
  const float* Wmv = (const float*)d_in[15];
  const float* We  = (const float*)d_in[16];
  const float* be  = (const float*)d_in[17];
  const float* Wme = (const float*)d_in[18];
  const float* gamma = (const float*)d_in[19];

  float* w = (float*)d_ws;
  // liveness-aliased layout (float offsets); peak ≈ 28.3 MB
  float* s_ln = w;                  // @0        786432  (s1 -> s5)
  float* r_ln = w + 786432;         //           196608  (s1 -> s2)
  float* WkT  = w + 983040;         //           393216  (s1 -> s3)
  float* qp   = w + 1376256;        //           524288  (s2 -> s3, 4 partials)
  float* sT   = w + 1900544;        //           786432  (s2 -> s4)
  float* cp   = w + 2686976;        //           720896  (s1 -> s7) [m][2816]
  float* qbk  = w + 3407872;        //             2048  (s3 -> s5)
  float* qm   = w + 3409920;        //          1572864  (s3 -> s4)
  float* scp  = w + 4982784;        //          2097152  (s4 -> s5, 4 partials)
  float* wsm  = qm;                 // alias (s5 -> s6)
  float* mmp  = r_ln;               // alias r_ln+WkT+qp region (s6 -> s7, 8 partials)
  float* op   = scp;                // alias (s7 -> s8, 8 partials)

  k_s1<<<dim3(1552), 256, 0, stream>>>(ss, rs, ln_s_g, ln_s_b, ln_r_g, ln_r_b,
                                       codes, Wmq, Wmk, Wmv, Wme, Wk,
                                       s_ln, r_ln, cp, WkT);
  k_s2<<<dim3(320), 256, 0, stream>>>(s_ln, r_ln, cp, Wq, sT, qp);
  k_s3<<<dim3(640), 256, 0, stream>>>(qp, bq, WkT, cp, bk, qm, qbk);
  k_s4<<<dim3(512), 256, 0, stream>>>(qm, sT, scp);
  k_s5<<<dim3(384), 256, 0, stream>>>(scp, qbk, s_ln, cp, wsm);
  k_s6<<<dim3(256), 256, 0, stream>>>(wsm, Wv, mmp);
  k_s7<<<dim3(384), 256, 0, stream>>>(mmp, bv, cp, We, op);
  k_s8<<<dim3(256), 256, 0, stream>>>(op, be, gamma, rs, (float*)d_out);
}